// Round 4
// baseline (450.030 us; speedup 1.0000x reference)
//
#include <hip/hip_runtime.h>
#include <hip/hip_bf16.h>
#include <math.h>

using bf16x8 = __attribute__((ext_vector_type(8))) __bf16;
using f32x4  = __attribute__((ext_vector_type(4))) float;
typedef unsigned short ushort_t;

#define BS    8192
#define CDIM  512
#define MROWS 32768
#define NC    8                 // n-chunks (grid.x)
#define CHUNK (MROWS / NC)      // 4096
#define TN    32                // B-tile rows per iteration
#define TQ    128               // queries per block
#define KTOP  5
#define ITERS (CHUNK / TN)      // 128
#define KEY_INIT 0x3FFF8000u    // enc_key(-2.0f, 0)

// ---------- key packing: monotonic fp32 order bits [31:15] | index [14:0] ----
__device__ __forceinline__ unsigned enc_key(float s, int n) {
    unsigned u = __float_as_uint(s);
    u ^= (unsigned)((int)u >> 31) | 0x80000000u;   // monotonic map
    return (u & 0xFFFF8000u) | (unsigned)n;
}
__device__ __forceinline__ float dec_score(unsigned k) {
    unsigned u = k & 0xFFFF8000u;
    u = (u & 0x80000000u) ? (u ^ 0x80000000u) : ~u;
    return __uint_as_float(u);
}

// sorted-descending top-5 list of packed keys, branchless bubble insert
__device__ __forceinline__ void ins_nb(unsigned (&ks)[KTOP], unsigned k) {
    unsigned t = k;
#pragma unroll
    for (int j = 0; j < KTOP; ++j) {
        unsigned hi = t > ks[j] ? t : ks[j];
        unsigned lo = t > ks[j] ? ks[j] : t;
        ks[j] = hi; t = lo;
    }
}

// ---------- kernel 1: row L2-normalize fp32 -> bf16 (both inputs, one grid) --
__global__ void nrm_cast2(const float* __restrict__ memM, ushort_t* __restrict__ mn,
                          const float* __restrict__ x, ushort_t* __restrict__ qn) {
    int wave = threadIdx.x >> 6, lane = threadIdx.x & 63;
    int row = blockIdx.x * 4 + wave;
    const float* in;
    ushort_t* out;
    if (row < MROWS) { in = memM + (size_t)row * CDIM; out = mn + (size_t)row * CDIM; }
    else             { int r = row - MROWS; in = x + (size_t)r * CDIM; out = qn + (size_t)r * CDIM; }
    const float* rp = in + lane * 8;
    float4 v0 = *(const float4*)rp;
    float4 v1 = *(const float4*)(rp + 4);
    float ss = v0.x * v0.x + v0.y * v0.y + v0.z * v0.z + v0.w * v0.w
             + v1.x * v1.x + v1.y * v1.y + v1.z * v1.z + v1.w * v1.w;
#pragma unroll
    for (int d = 1; d < 64; d <<= 1) ss += __shfl_xor(ss, d);
    float sc = 1.0f / fmaxf(sqrtf(ss), 1e-12f);
    bf16x8 o;
    o[0] = (__bf16)(v0.x * sc); o[1] = (__bf16)(v0.y * sc);
    o[2] = (__bf16)(v0.z * sc); o[3] = (__bf16)(v0.w * sc);
    o[4] = (__bf16)(v1.x * sc); o[5] = (__bf16)(v1.y * sc);
    o[6] = (__bf16)(v1.z * sc); o[7] = (__bf16)(v1.w * sc);
    *(bf16x8*)(out + lane * 8) = o;
}

// ---------- async staging with XOR chunk swizzle ----------------------------
// LDS tile: row r occupies 64 uint4 slots [r*64, r*64+64). Global 16B-chunk c
// of row r is stored at slot c ^ (r&7): the DMA's LDS side is fixed
// (base + lane*16), so lane i sources global chunk i ^ (r&7) — the XOR stays
// inside a 128B window, keeping the global read fully coalesced.
__device__ __forceinline__ void stage_tile(const ushort_t* __restrict__ mn, int nb,
                                           uint4* buf, int wave, int lane) {
    const int r0 = wave * 8;
#pragma unroll
    for (int j = 0; j < 8; ++j) {
        const int row = r0 + j;
        const ushort_t* src = mn + (size_t)(nb + row) * CDIM + ((lane ^ (row & 7)) * 8);
        __builtin_amdgcn_global_load_lds(
            (const __attribute__((address_space(1))) void*)src,
            (__attribute__((address_space(3))) void*)(buf + row * 64),
            16, 0, 0);
    }
}

// ---------- kernel 2: fused bf16 MFMA sim + per-chunk top-5 -----------------
// grid = (NC, BS/TQ), block = 256 (4 waves). Wave owns 32 queries (A persistent
// in registers), computes 32q x 32n per tile, K=512 inner. Double-buffered
// async DMA staging, ONE barrier per iteration (the s_waitcnt vmcnt(0) the
// compiler emits before s_barrier drains loads issued a full iteration ago).
__global__ __launch_bounds__(256, 2) void simtopk(
        const ushort_t* __restrict__ qn, const ushort_t* __restrict__ mn,
        unsigned* __restrict__ cand) {
    __shared__ uint4 Bt[2][TN * 64];          // 2 x 32 KiB = 65536 B exactly

    const int tid  = threadIdx.x;
    const int wave = tid >> 6, lane = tid & 63;
    const int quad = lane >> 4, c16 = lane & 15;
    const int nc = blockIdx.x;                 // fast-varying -> XCD-local B chunk
    const int qt = blockIdx.y;
    const int qw = qt * TQ + wave * 32;
    const int nb0 = nc * CHUNK;

    // persistent A fragments: 2 q-subtiles x 16 K-chunks
    bf16x8 a0[16], a1[16];
    {
        const ushort_t* p0 = qn + (size_t)(qw + c16) * CDIM + quad * 8;
#pragma unroll
        for (int kc = 0; kc < 16; ++kc) {
            a0[kc] = *(const bf16x8*)(p0 + kc * 32);
            a1[kc] = *(const bf16x8*)(p0 + 16 * CDIM + kc * 32);
        }
    }

    unsigned keys[8][KTOP];
    float thr[8];
#pragma unroll
    for (int l = 0; l < 8; ++l) {
        thr[l] = -2.0f;
#pragma unroll
        for (int j = 0; j < KTOP; ++j) keys[l][j] = KEY_INIT;
    }

    const int sw = c16 & 7;                    // read-side slot XOR (row&7 for both
                                               // rows c16 and 16+c16)

    // prefetch tile 0
    stage_tile(mn, nb0, &Bt[0][0], wave, lane);

    for (int it = 0; it < ITERS; ++it) {
        __syncthreads();   // drains async loads issued a full iter ago; syncs waves
        if (it + 1 < ITERS)
            stage_tile(mn, nb0 + (it + 1) * TN, &Bt[(it + 1) & 1][0], wave, lane);

        const uint4* bb = &Bt[it & 1][c16 * 64];
        f32x4 acc00 = {0.f, 0.f, 0.f, 0.f}, acc01 = {0.f, 0.f, 0.f, 0.f};
        f32x4 acc10 = {0.f, 0.f, 0.f, 0.f}, acc11 = {0.f, 0.f, 0.f, 0.f};
#pragma unroll
        for (int kc = 0; kc < 16; ++kc) {
            const int slot = (kc * 4 + quad) ^ sw;
            bf16x8 b0 = *(const bf16x8*)(bb + slot);              // row c16
            bf16x8 b1 = *(const bf16x8*)(bb + 16 * 64 + slot);    // row 16+c16
            acc00 = __builtin_amdgcn_mfma_f32_16x16x32_bf16(a0[kc], b0, acc00, 0, 0, 0);
            acc01 = __builtin_amdgcn_mfma_f32_16x16x32_bf16(a0[kc], b1, acc01, 0, 0, 0);
            acc10 = __builtin_amdgcn_mfma_f32_16x16x32_bf16(a1[kc], b0, acc10, 0, 0, 0);
            acc11 = __builtin_amdgcn_mfma_f32_16x16x32_bf16(a1[kc], b1, acc11, 0, 0, 0);
        }

        const int nb = nb0 + it * TN;
        const int n0 = nb + c16, n1 = nb + 16 + c16;
        // shared-threshold filter: thr[l] <= true running 5th-best of query l
        // -> hot path is 1 float cmp per score; encode+insert is rare.
#pragma unroll
        for (int j = 0; j < 4; ++j) {
            if (acc00[j] > thr[j])     ins_nb(keys[j],     enc_key(acc00[j], n0));
            if (acc01[j] > thr[j])     ins_nb(keys[j],     enc_key(acc01[j], n1));
            if (acc10[j] > thr[4 + j]) ins_nb(keys[4 + j], enc_key(acc10[j], n0));
            if (acc11[j] > thr[4 + j]) ins_nb(keys[4 + j], enc_key(acc11[j], n1));
        }
        if ((it & 3) == 3) {
            // thr[l] = max over the 16 column-shards of each shard's 5th-best
#pragma unroll
            for (int l = 0; l < 8; ++l) {
                float t = fmaxf(thr[l], dec_score(keys[l][KTOP - 1]));
#pragma unroll
                for (int d = 1; d <= 8; d <<= 1) t = fmaxf(t, __shfl_xor(t, d));
                thr[l] = t;
            }
        }
    }

    // merge the 16 column-lanes of each quad (disjoint n subsets -> union top5)
#pragma unroll
    for (int d = 1; d <= 8; d <<= 1) {
#pragma unroll
        for (int l = 0; l < 8; ++l) {
            unsigned rk[KTOP];
#pragma unroll
            for (int j = 0; j < KTOP; ++j) rk[j] = (unsigned)__shfl_xor((int)keys[l][j], d);
#pragma unroll
            for (int j = 0; j < KTOP; ++j) ins_nb(keys[l], rk[j]);
        }
    }

    // writer lane c16==l emits list l for query qw + qs*16 + quad*4 + r
#pragma unroll
    for (int l = 0; l < 8; ++l) {
        if (c16 == l) {
            const int qs = l >> 2, r = l & 3;
            const int q = qw + qs * 16 + quad * 4 + r;
            unsigned* cp = cand + ((size_t)q * NC + nc) * KTOP;
#pragma unroll
            for (int j = 0; j < KTOP; ++j) cp[j] = keys[l][j];
        }
    }
}

// ---------- kernel 3: global top-5 merge + softmax + gather + residual ------
__global__ void epilogue(const float* __restrict__ x, const float* __restrict__ mem,
                         const unsigned* __restrict__ cand, float* __restrict__ out) {
    int wave = threadIdx.x >> 6, lane = threadIdx.x & 63;
    int q = blockIdx.x * 4 + wave;

    unsigned key = (lane < NC * KTOP) ? cand[(size_t)q * (NC * KTOP) + lane] : 0u;
    float s[KTOP]; int id[KTOP];
#pragma unroll
    for (int k = 0; k < KTOP; ++k) {
        unsigned m = key;
#pragma unroll
        for (int d = 32; d; d >>= 1) {
            unsigned o = (unsigned)__shfl_xor((int)m, d);
            m = o > m ? o : m;
        }
        s[k] = dec_score(m);
        id[k] = (int)(m & 0x7FFFu);
        unsigned long long b = __ballot(key == m);
        int first = __ffsll((long long)b) - 1;
        if (lane == first) key = 0u;
    }
    float w[KTOP], sum = 0.f;
#pragma unroll
    for (int k = 0; k < KTOP; ++k) { w[k] = expf(s[k] - s[0]); sum += w[k]; }
    float inv = 0.5f / sum;

    int c = lane * 8;
    const float4* xp = (const float4*)(x + (size_t)q * CDIM + c);
    float4 o0 = xp[0], o1 = xp[1];
#pragma unroll
    for (int k = 0; k < KTOP; ++k) {
        float wk = w[k] * inv;
        const float4* mp = (const float4*)(mem + (size_t)id[k] * CDIM + c);
        float4 g0 = mp[0], g1 = mp[1];
        o0.x += wk * g0.x; o0.y += wk * g0.y; o0.z += wk * g0.z; o0.w += wk * g0.w;
        o1.x += wk * g1.x; o1.y += wk * g1.y; o1.z += wk * g1.z; o1.w += wk * g1.w;
    }
    float* op = out + (size_t)q * CDIM + c;
    *(float4*)op = o0;
    *(float4*)(op + 4) = o1;
}

// ---------- launcher --------------------------------------------------------
extern "C" void kernel_launch(void* const* d_in, const int* in_sizes, int n_in,
                              void* d_out, int out_size, void* d_ws, size_t ws_size,
                              hipStream_t stream) {
    const float* x    = (const float*)d_in[0];   // [4,2048,512] fp32
    const float* memM = (const float*)d_in[1];   // [32768,512] fp32
    float* out = (float*)d_out;                  // fp32 output

    // workspace layout: mn bf16 [M][C] | qn bf16 [BS][C] | cand u32 [BS][NC][5]
    ushort_t* mn = (ushort_t*)d_ws;
    ushort_t* qn = mn + (size_t)MROWS * CDIM;
    unsigned* cand = (unsigned*)(qn + (size_t)BS * CDIM);

    nrm_cast2<<<(MROWS + BS) / 4, 256, 0, stream>>>(memM, mn, x, qn);
    simtopk<<<dim3(NC, BS / TQ), 256, 0, stream>>>(qn, mn, cand);
    epilogue<<<BS / 4, 256, 0, stream>>>(x, memM, cand, out);
}